// Round 1
// baseline (177.416 us; speedup 1.0000x reference)
//
#include <hip/hip_runtime.h>

#define T_DIM 64
#define NP 4096                      /* total (n,c) pairs */
#define D_OUTC 129
#define ROW_STRIDE (NP * D_OUTC)     /* floats between t-slices */
#define PPB 4                        /* adjacent p's per block -> 2064B contiguous span per t */
#define NBLK_P (NP / PPB)            /* 1024 p-groups */
#define TSPLIT 2                     /* each p-group split into 2 t-halves -> 2048 blocks */

typedef float v2f __attribute__((ext_vector_type(2)));

// Closed form: with z=[x;x], H[i] = sum_{j<=i} decay^{i-j} z[j] (i in 0..127),
// shifted+filtered series y_s[t] = H[64-s+t] - decay^{t+1} * H[63-s].
// out[t,p,d] = w*(y_{s0}^{ch0}[t] + y_{s1}^{ch1}[t]); w folded into H.
//
// R0 discriminating experiment (see journal): kernel modeled store-BW-bound
// (~25us vs 20.7us floor); this version attacks every NON-BW candidate:
//  - TSPLIT=2: 2048 blocks x 32 t-steps, launch_bounds(256,6) -> 24 waves/CU
//    (was 16) for latency hiding. Setup scan duplicated (~1us/block, cheap).
//  - uniform-channel share: for each element one channel has s==0 exactly
//    (relu kills one side of +/-dp; u<0 never fires; caps>=0). Paired elements
//    share that broadcast series for 125/129 pairs -> guarded 4th LDS read.
//  - nontemporal stores: out is write-once, keep it out of L2/L3 allocation.
// Math and store pattern unchanged -> bitwise-identical output.
__global__ __launch_bounds__(256, 6) void jeffress_kernel(
    const float* __restrict__ input,        // (T, N, C, 2)
    const float* __restrict__ delay_param,  // (129, 1)
    const float* __restrict__ weight,       // scalar
    const float* __restrict__ u,            // (N, C, 129, 2)
    float* __restrict__ out)                // (T, N, C, 129)
{
    __shared__ float Hw[PPB * 2 * 128];    // [p_local][ch][i], w-scaled
    __shared__ int caps[PPB][2];           // 63 - argmax_t

    const int blk = blockIdx.x;            // [0, 2048)
    const int gb  = blk & (NBLK_P - 1);    // p-group pre-swizzle
    const int th  = blk >> 10;             // t-half: 0 -> t in [0,32), 1 -> [32,64)
    // XCD swizzle: adjacent groups share an XCD so boundary lines merge in its L2.
    // Both t-halves of a group keep the same (blk&7) -> same XCD.
    const int g   = ((gb & 7) << 7) | (gb >> 3);     // [0,1024)
    const int p0  = g * PPB;
    const int tid = threadIdx.x;
    const int lane = tid & 63, wv = tid >> 6;        // wave wv owns p_local = wv
    const float DECAY = 0.6065306597126334f;         // exp(-1/2), f32 as reference
    const float w = weight[0];

    // ---- setup: per-wave load, argmax, dual-channel weighted Kogge-Stone scan ----
    {
        float2 xp = ((const float2*)input)[lane * NP + p0 + wv];
        #pragma unroll
        for (int ch = 0; ch < 2; ++ch) {             // first-occurrence argmax
            float xv = ch ? xp.y : xp.x;
            unsigned b = __float_as_uint(xv);
            b ^= (b & 0x80000000u) ? 0xffffffffu : 0x80000000u;  // total float order
            unsigned long long key = ((unsigned long long)b << 32) | (unsigned)(63 - lane);
            #pragma unroll
            for (int mm = 1; mm < 64; mm <<= 1) {
                unsigned long long o = __shfl_xor(key, mm, 64);
                if (o > key) key = o;                // ties -> larger (63-t) -> first t
            }
            if (lane == 0) caps[wv][ch] = (int)(key & 0xffffffffull);
        }
        float v0 = xp.x, v1 = xp.y;
        const float dks[6] = {0.6065306597126334f,     // decay^1
                              0.36787944117144233f,    // decay^2
                              0.1353352832366127f,     // decay^4
                              0.01831563888873418f,    // decay^8
                              3.3546262790251185e-4f,  // decay^16
                              1.1253517471925912e-7f}; // decay^32
        #pragma unroll
        for (int k = 0; k < 6; ++k) {
            int o = 1 << k;
            float q0 = __shfl_up(v0, o, 64);
            float q1 = __shfl_up(v1, o, 64);
            if (lane >= o) { v0 += dks[k] * q0; v1 += dks[k] * q1; }
        }
        float h063 = __shfl(v0, 63, 64);
        float h163 = __shfl(v1, 63, 64);
        float f = exp2f(-0.7213475204444817f * (float)(lane + 1)); // decay^{lane+1}
        float* H0 = &Hw[(wv * 2 + 0) * 128];
        float* H1 = &Hw[(wv * 2 + 1) * 128];
        H0[lane] = w * v0;  H0[64 + lane] = w * (v0 + f * h063);
        H1[lane] = w * v1;  H1[64 + lane] = w * (v1 + f * h163);
    }
    __syncthreads();

    // ---- per-element descriptors; split into varying (ov) + uniform (ou) channel.
    // d<=64: s0==0 deterministically (b0=relu(dp)=0 -> frac 0 -> u<0 false; caps>=0)
    // d>=64: s1==0 likewise. ou always points at the s=0 series (base+64).
    auto mke = [&](int q, int& ov, int& ou, float& Cw) {   // q in [0, 516)
        int pl = q / 129;
        int d  = q - 129 * pl;
        float dp = delay_param[d];
        float b0 = fmaxf(dp, 0.0f), b1 = fmaxf(-dp, 0.0f);  // relu(cat([dp,-dp]))
        float2 uu = ((const float2*)u)[(p0 + pl) * D_OUTC + d];
        float f0 = floorf(b0), f1 = floorf(b1);
        float r0 = (uu.x < b0 - f0) ? f0 + 1.0f : f0;
        float r1 = (uu.y < b1 - f1) ? f1 + 1.0f : f1;
        int s0 = (int)fminf(r0, (float)caps[pl][0]);
        int s1 = (int)fminf(r1, (float)caps[pl][1]);
        int o0 = (pl * 2 + 0) * 128 + 64 - s0;    // gather base; +t stays in [1,127]
        int o1 = (pl * 2 + 1) * 128 + 64 - s1;
        if (d <= 64) { ou = o0; ov = o1; } else { ou = o1; ov = o0; }
        Cw = Hw[ov - 1] + Hw[ou - 1];             // w*(H0[63-s0]+H1[63-s1]) (commutative)
    };

    int oAv, oAu, oBv, oBu; float CwA, CwB;
    mke(2 * tid,     oAv, oAu, CwA);
    mke(2 * tid + 1, oBv, oBu, CwB);
    const bool sameAB = (oAu == oBu);             // true for 125/129 pairs
    const bool xtra = (tid < 2);                  // float2 #256,#257 (elements 512..515)
    int oCv = 0, oCu = 0, oDv = 0, oDu = 0; float CwC = 0.0f, CwDd = 0.0f;
    bool sameCD = true;
    if (xtra) {
        mke(512 + 2 * tid, oCv, oCu, CwC);
        mke(513 + 2 * tid, oDv, oDu, CwDd);
        sameCD = (oCu == oDu);
    }

    float* rp  = out + (size_t)p0 * D_OUTC + 2 * tid;         // 8B-aligned
    float* rpx = out + (size_t)p0 * D_OUTC + 512 + 2 * tid;

    const float K[8] = {1.0f, 0.6065306597126334f, 0.36787944117144233f,
                        0.22313016014842982f, 0.1353352832366127f,
                        0.0820849986238988f, 0.049787068367863944f,
                        0.030197383422318501f};  // decay^j
    // decay^{t0+1}: th=0 -> decay^1; th=1 -> decay^33 = decay * decay^32
    float Dg = th ? DECAY * 1.1253517471925912e-7f : DECAY;

    const int t0 = th << 5;
    for (int tg = t0; tg < t0 + 32; tg += 8) {
        float cA = CwA * Dg, cB = CwB * Dg;
        float cC = CwC * Dg, cD = CwDd * Dg;
        #pragma unroll
        for (int j = 0; j < 8; ++j) {
            int t = tg + j;
            float uA = Hw[oAu + t];
            float uB = uA;
            if (!sameAB) uB = Hw[oBu + t];        // skipped for most waves
            v2f v;
            v.x = Hw[oAv + t] + uA - K[j] * cA;   // 1 gather + 1 (mostly shared) broadcast
            v.y = Hw[oBv + t] + uB - K[j] * cB;
            __builtin_nontemporal_store(v, (v2f*)(rp + (size_t)t * ROW_STRIDE));
            if (xtra) {
                float uC = Hw[oCu + t];
                float uD = uC;
                if (!sameCD) uD = Hw[oDu + t];
                v2f vx;
                vx.x = Hw[oCv + t] + uC - K[j] * cC;
                vx.y = Hw[oDv + t] + uD - K[j] * cD;
                __builtin_nontemporal_store(vx, (v2f*)(rpx + (size_t)t * ROW_STRIDE));
            }
        }
        Dg *= 0.01831563888873418f;              // decay^8
    }
}

extern "C" void kernel_launch(void* const* d_in, const int* in_sizes, int n_in,
                              void* d_out, int out_size, void* d_ws, size_t ws_size,
                              hipStream_t stream) {
    const float* input       = (const float*)d_in[0]; // (64,16,256,2)
    const float* delay_param = (const float*)d_in[1]; // (129,1)
    const float* weight      = (const float*)d_in[2]; // scalar
    const float* u           = (const float*)d_in[3]; // (16,256,129,2)
    float* out = (float*)d_out;                       // (64,16,256,129)

    jeffress_kernel<<<NBLK_P * TSPLIT, 256, 0, stream>>>(input, delay_param, weight, u, out);
}

// Round 2
// 155.919 us; speedup vs baseline: 1.1379x; 1.1379x over previous
//
#include <hip/hip_runtime.h>

#define T_DIM 64
#define NP 4096                      /* total (n,c) pairs */
#define D_OUTC 129
#define ROW_STRIDE (NP * D_OUTC)     /* floats between t-slices */
#define PPB 4                        /* adjacent p's per block -> 2064B contiguous span per t */

typedef float v2f __attribute__((ext_vector_type(2)));

// Closed form: with z=[x;x], H[i] = sum_{j<=i} decay^{i-j} z[j] (i in 0..127),
// shifted+filtered series y_s[t] = H[64-s+t] - decay^{t+1} * H[63-s].
// out[t,p,d] = w*(y_{s0}^{ch0}[t] + y_{s1}^{ch1}[t]); w folded into H.
// Block = 4 adjacent p: per t writes one contiguous 16B-aligned 2064B span
// (full 64B lines except 2 boundary partials merged with same-XCD neighbors).
//
// R1 post-mortem: the R0->R1 A/B (TSPLIT=2 + launch_bounds(256,6) + NT stores)
// regressed 157->177us (~6us of it machine drift; fills slowed 6.53->6.31 TB/s).
// Conclusions: (a) kernel is NOT latency/occupancy-bound -- raising waves/CU
// hurt via the 80-VGPR cap (spills in the hot store loop); (b) NT stores defeat
// the L2 boundary-line merge the XCD swizzle exists for; (c) setup duplication
// costs ~5us aggregate. This file is the exact proven R0 baseline (156.9us):
// store-BW-bound at ~25us vs 20.7us floor; residual headroom < session noise.
__global__ __launch_bounds__(256, 4) void jeffress_kernel(
    const float* __restrict__ input,        // (T, N, C, 2)
    const float* __restrict__ delay_param,  // (129, 1)
    const float* __restrict__ weight,       // scalar
    const float* __restrict__ u,            // (N, C, 129, 2)
    float* __restrict__ out)                // (T, N, C, 129)
{
    __shared__ float Hw[PPB * 2 * 128];    // [p_local][ch][i], w-scaled
    __shared__ int caps[PPB][2];           // 63 - argmax_t

    const int blk = blockIdx.x;
    // XCD swizzle: adjacent groups share an XCD so boundary lines merge in its L2
    const int g   = ((blk & 7) << 7) | (blk >> 3);   // [0,1024)
    const int p0  = g * PPB;
    const int tid = threadIdx.x;
    const int lane = tid & 63, wv = tid >> 6;        // wave wv owns p_local = wv
    const float DECAY = 0.6065306597126334f;         // exp(-1/2), f32 as reference
    const float w = weight[0];

    // ---- setup: per-wave load, argmax, dual-channel weighted Kogge-Stone scan ----
    {
        float2 xp = ((const float2*)input)[lane * NP + p0 + wv];
        #pragma unroll
        for (int ch = 0; ch < 2; ++ch) {             // first-occurrence argmax
            float xv = ch ? xp.y : xp.x;
            unsigned b = __float_as_uint(xv);
            b ^= (b & 0x80000000u) ? 0xffffffffu : 0x80000000u;  // total float order
            unsigned long long key = ((unsigned long long)b << 32) | (unsigned)(63 - lane);
            #pragma unroll
            for (int mm = 1; mm < 64; mm <<= 1) {
                unsigned long long o = __shfl_xor(key, mm, 64);
                if (o > key) key = o;                // ties -> larger (63-t) -> first t
            }
            if (lane == 0) caps[wv][ch] = (int)(key & 0xffffffffull);
        }
        float v0 = xp.x, v1 = xp.y;
        const float dks[6] = {0.6065306597126334f,     // decay^1
                              0.36787944117144233f,    // decay^2
                              0.1353352832366127f,     // decay^4
                              0.01831563888873418f,    // decay^8
                              3.3546262790251185e-4f,  // decay^16
                              1.1253517471925912e-7f}; // decay^32
        #pragma unroll
        for (int k = 0; k < 6; ++k) {
            int o = 1 << k;
            float q0 = __shfl_up(v0, o, 64);
            float q1 = __shfl_up(v1, o, 64);
            if (lane >= o) { v0 += dks[k] * q0; v1 += dks[k] * q1; }
        }
        float h063 = __shfl(v0, 63, 64);
        float h163 = __shfl(v1, 63, 64);
        float f = exp2f(-0.7213475204444817f * (float)(lane + 1)); // decay^{lane+1}
        float* H0 = &Hw[(wv * 2 + 0) * 128];
        float* H1 = &Hw[(wv * 2 + 1) * 128];
        H0[lane] = w * v0;  H0[64 + lane] = w * (v0 + f * h063);
        H1[lane] = w * v1;  H1[64 + lane] = w * (v1 + f * h163);
    }
    __syncthreads();

    // ---- per-element descriptors (generic stochastic rounding + clamp) ----
    auto mke = [&](int q, int& o0, int& o1, float& Cw) {   // q in [0, 516)
        int pl = q / 129;
        int d  = q - 129 * pl;
        float dp = delay_param[d];
        float b0 = fmaxf(dp, 0.0f), b1 = fmaxf(-dp, 0.0f);  // relu(cat([dp,-dp]))
        float2 uu = ((const float2*)u)[(p0 + pl) * D_OUTC + d];
        float f0 = floorf(b0), f1 = floorf(b1);
        float r0 = (uu.x < b0 - f0) ? f0 + 1.0f : f0;
        float r1 = (uu.y < b1 - f1) ? f1 + 1.0f : f1;
        int s0 = (int)fminf(r0, (float)caps[pl][0]);
        int s1 = (int)fminf(r1, (float)caps[pl][1]);
        o0 = (pl * 2 + 0) * 128 + 64 - s0;    // gather base; +t stays in [1,127]
        o1 = (pl * 2 + 1) * 128 + 64 - s1;
        Cw = Hw[o0 - 1] + Hw[o1 - 1];         // w*(H0[63-s0]+H1[63-s1])
    };

    int oA0, oA1, oB0, oB1; float CwA, CwB;
    mke(2 * tid,     oA0, oA1, CwA);
    mke(2 * tid + 1, oB0, oB1, CwB);
    const bool xtra = (tid < 2);              // float2 #256,#257 (elements 512..515)
    int oC0 = 0, oC1 = 0, oD0 = 0, oD1 = 0; float CwC = 0.0f, CwDd = 0.0f;
    if (xtra) {
        mke(512 + 2 * tid, oC0, oC1, CwC);
        mke(513 + 2 * tid, oD0, oD1, CwDd);
    }

    float* rp  = out + (size_t)p0 * D_OUTC + 2 * tid;         // 8B-aligned
    float* rpx = out + (size_t)p0 * D_OUTC + 512 + 2 * tid;

    const float K[8] = {1.0f, 0.6065306597126334f, 0.36787944117144233f,
                        0.22313016014842982f, 0.1353352832366127f,
                        0.0820849986238988f, 0.049787068367863944f,
                        0.030197383422318501f};  // decay^j
    float Dg = DECAY;                            // decay^{tg+1}

    for (int tg = 0; tg < T_DIM; tg += 8) {
        float cA = CwA * Dg, cB = CwB * Dg;
        float cC = CwC * Dg, cD = CwDd * Dg;
        #pragma unroll
        for (int j = 0; j < 8; ++j) {
            int t = tg + j;
            v2f v;
            v.x = Hw[oA0 + t] + Hw[oA1 + t] - K[j] * cA;  // 1 gather + 1 broadcast
            v.y = Hw[oB0 + t] + Hw[oB1 + t] - K[j] * cB;
            *(v2f*)(rp + (size_t)t * ROW_STRIDE) = v;     // contiguous 2064B block-span
            if (xtra) {
                v2f vx;
                vx.x = Hw[oC0 + t] + Hw[oC1 + t] - K[j] * cC;
                vx.y = Hw[oD0 + t] + Hw[oD1 + t] - K[j] * cD;
                *(v2f*)(rpx + (size_t)t * ROW_STRIDE) = vx;
            }
        }
        Dg *= 0.01831563888873418f;              // decay^8
    }
}

extern "C" void kernel_launch(void* const* d_in, const int* in_sizes, int n_in,
                              void* d_out, int out_size, void* d_ws, size_t ws_size,
                              hipStream_t stream) {
    const float* input       = (const float*)d_in[0]; // (64,16,256,2)
    const float* delay_param = (const float*)d_in[1]; // (129,1)
    const float* weight      = (const float*)d_in[2]; // scalar
    const float* u           = (const float*)d_in[3]; // (16,256,129,2)
    float* out = (float*)d_out;                       // (64,16,256,129)

    jeffress_kernel<<<NP / PPB, 256, 0, stream>>>(input, delay_param, weight, u, out);
}